// Round 1
// baseline (259.249 us; speedup 1.0000x reference)
//
#include <hip/hip_runtime.h>
#include <math.h>

// excess[b,m] = sum_n K[m,n]*T[b,n] + SIGMA*e[m]*(T[b,m]^4 - Tenv[b]^4) - (H[b,m]+F[b,m])
// out = mean(|excess|).  K is a 5-band stencil (cols m, m+-1, m+-13); bands read from
// the real K input into LDS (no hardcoded constants). Memory-bound: 3 x 88.6 MB streams.

#define SIGMA_F 5.67e-8f

constexpr int NN = 169;      // 13*13 nodes
constexpr int BLOCK = 256;
constexpr int GRID = 2048;   // 8 blocks/CU on 256 CUs

__global__ __launch_bounds__(256) void fused_residual_kernel(
    const float* __restrict__ T,      // outputs, flat [B*169]
    const float* __restrict__ H,      // heaters
    const float* __restrict__ F,      // interfaces
    const float* __restrict__ Tenv,   // [B]
    const float* __restrict__ K,      // [169*169]
    const float* __restrict__ Ediag,  // [169]
    float* __restrict__ partials,     // [gridDim.x]
    int total)
{
    __shared__ float sD[NN], sE[NN], sW[NN], sN[NN], sS[NN], sR[NN];
    __shared__ float sred[BLOCK / 64];

    // Stage the 5 bands of K + e_diag into LDS once per block.
    for (int m = (int)threadIdx.x; m < NN; m += BLOCK) {
        const float* row = K + m * NN;
        sD[m] = row[m];
        sE[m] = (m + 1  < NN) ? row[m + 1]  : 0.0f;
        sW[m] = (m >= 1)      ? row[m - 1]  : 0.0f;
        sN[m] = (m + 13 < NN) ? row[m + 13] : 0.0f;
        sS[m] = (m >= 13)     ? row[m - 13] : 0.0f;
        sR[m] = Ediag[m];
    }
    __syncthreads();

    float acc = 0.0f;
    const int stride = gridDim.x * blockDim.x;
    for (int e = blockIdx.x * blockDim.x + threadIdx.x; e < total; e += stride) {
        unsigned ue = (unsigned)e;
        unsigned b  = ue / 169u;            // compiler -> magic mul_hi
        int m = (int)(ue - b * 169u);

        // Clamped neighbor indices: clamp only fires where the band is 0.0f,
        // so values are exact and loads stay in-bounds.
        int es = e - 13; es = es < 0 ? 0 : es;
        int en = e + 13; en = en >= total ? total - 1 : en;
        int ew = e - 1;  ew = ew < 0 ? 0 : ew;
        int ee = e + 1;  ee = ee >= total ? total - 1 : ee;

        float t  = T[e];
        float tS = T[es];
        float tN = T[en];
        float tW = T[ew];
        float tE = T[ee];

        float cond = sD[m] * t + sE[m] * tE + sW[m] * tW + sN[m] * tN + sS[m] * tS;

        float tv  = Tenv[b];
        float t2  = t * t;
        float tv2 = tv * tv;
        float rad = SIGMA_F * sR[m] * (t2 * t2 - tv2 * tv2);

        float q = H[e] + F[e];
        acc += fabsf(cond + rad - q);
    }

    // wave (64-lane) shuffle reduction
    #pragma unroll
    for (int off = 32; off > 0; off >>= 1)
        acc += __shfl_down(acc, off, 64);

    int lane = threadIdx.x & 63;
    int wid  = threadIdx.x >> 6;
    if (lane == 0) sred[wid] = acc;
    __syncthreads();
    if (threadIdx.x == 0) {
        float s = 0.0f;
        #pragma unroll
        for (int w = 0; w < BLOCK / 64; ++w) s += sred[w];
        partials[blockIdx.x] = s;
    }
}

__global__ __launch_bounds__(256) void finalize_kernel(
    const float* __restrict__ partials, int n,
    float* __restrict__ out, float inv_total)
{
    __shared__ float sred[BLOCK / 64];
    float acc = 0.0f;
    for (int i = (int)threadIdx.x; i < n; i += BLOCK) acc += partials[i];
    #pragma unroll
    for (int off = 32; off > 0; off >>= 1)
        acc += __shfl_down(acc, off, 64);
    int lane = threadIdx.x & 63;
    int wid  = threadIdx.x >> 6;
    if (lane == 0) sred[wid] = acc;
    __syncthreads();
    if (threadIdx.x == 0) {
        float s = 0.0f;
        #pragma unroll
        for (int w = 0; w < BLOCK / 64; ++w) s += sred[w];
        out[0] = s * inv_total;
    }
}

extern "C" void kernel_launch(void* const* d_in, const int* in_sizes, int n_in,
                              void* d_out, int out_size, void* d_ws, size_t ws_size,
                              hipStream_t stream) {
    const float* T    = (const float*)d_in[0];  // outputs   [B*169]
    const float* H    = (const float*)d_in[1];  // heaters   [B*169]
    const float* F    = (const float*)d_in[2];  // interfaces[B*169]
    const float* Tenv = (const float*)d_in[3];  // [B]
    const float* K    = (const float*)d_in[4];  // [169*169]
    const float* E    = (const float*)d_in[5];  // [169]
    float* out      = (float*)d_out;
    float* partials = (float*)d_ws;

    const int total = in_sizes[0];              // 131072 * 169

    int grid = GRID;
    // Safety: never write more partials than the workspace holds.
    if ((size_t)grid * sizeof(float) > ws_size) grid = (int)(ws_size / sizeof(float));
    if (grid < 1) grid = 1;

    fused_residual_kernel<<<grid, BLOCK, 0, stream>>>(T, H, F, Tenv, K, E, partials, total);

    const float inv_total = 1.0f / (float)total;
    finalize_kernel<<<1, BLOCK, 0, stream>>>(partials, grid, out, inv_total);
}